// Round 11
// baseline (281.835 us; speedup 1.0000x reference)
//
#include <hip/hip_runtime.h>
#include <math.h>

// Problem constants
static constexpr int BB = 4;
static constexpr int NN = 16384;
static constexpr int KK = 8;
static constexpr int EE = 131072;   // edges per batch
static constexpr int RR = 65536;    // BB*NN rows
static constexpr int EG = 524288;   // total edges

// Stats: 64 planes x 512 floats per BN slot
static constexpr int SPL = 64;
static constexpr size_t SLOT = (size_t)SPL*512;

// Workspace layout (float offsets)
static constexpr size_t OFF_X0 = 0;
static constexpr size_t OFF_X1 = OFF_X0 + (size_t)RR*32;
static constexpr size_t OFF_X2 = OFF_X1 + (size_t)RR*64;
static constexpr size_t OFF_X3 = OFF_X2 + (size_t)RR*128;
static constexpr size_t OFF_ZB = OFF_X3 + (size_t)RR*256; // fp16 b-branch
static constexpr size_t OFF_ZC = OFF_ZB + (size_t)RR*128; // 65536 fp32
static constexpr size_t OFF_S  = OFF_ZC + (size_t)RR;     // 9 slots * SLOT
static constexpr size_t OFF_WP = OFF_S + 9*SLOT;          // packed fp16 weights
static constexpr size_t OFF_MX = OFF_WP + 65536;          // layer-0 edge max (RR*32 fp32)
static constexpr size_t WP1_OFF = 0;
static constexpr size_t WP2_OFF = 4096;
static constexpr size_t WP3_OFF = 4096 + 16384;

__device__ __forceinline__ float lrelu(float x) { return fmaxf(x, 0.2f*x); }

__device__ __forceinline__ unsigned short f2h(float f) {
    _Float16 h = (_Float16)f;
    return *(unsigned short*)&h;
}
__device__ __forceinline__ float h2f(unsigned short u) {
    _Float16 h = *(_Float16*)&u;
    return (float)h;
}

typedef __attribute__((ext_vector_type(8))) _Float16 half8v;
typedef __attribute__((ext_vector_type(8))) unsigned short ushort8v;
typedef __attribute__((ext_vector_type(4))) float float4v;

// packed fp16 elementwise max (v_pk_max_f16); fp16 compare is exact, so the
// gather-max computed in fp16 over fp16 data is bit-identical to the f32 path.
__device__ __forceinline__ half8v h8max(half8v a, half8v b) {
#if __has_builtin(__builtin_elementwise_max)
    return __builtin_elementwise_max(a, b);
#else
    half8v r;
#pragma unroll
    for (int j = 0; j < 8; ++j) r[j] = (a[j] > b[j]) ? a[j] : b[j];
    return r;
#endif
}

// ---- layer 0 FUSED: a-branch GEMM 8->32 (pre-BN fp16 out) + a-stats +
// b-branch edge MLP over each center's 8 edges computing b-stats AND the
// sign-folded per-center max in ONE gather pass. Quad-split: 4 lanes per
// center, 8 cols each. Neighbor rows preloaded to regs for latency overlap.
__global__ __launch_bounds__(256) void k_l0_fused(const float* __restrict__ xf,
                                                  const int* __restrict__ ei,
                                                  const float* __restrict__ Wa,
                                                  const float* __restrict__ Wb,
                                                  const float* __restrict__ gb,
                                                  unsigned short* __restrict__ xa,
                                                  float* __restrict__ mxb,
                                                  float* __restrict__ Sa,
                                                  float* __restrict__ Sb) {
    __shared__ float wa[256], wb[256];
    __shared__ float red[128];
    __shared__ float sgns[32];
    int tid = threadIdx.x;
    wa[tid] = Wa[tid];
    wb[tid] = Wb[tid];
    if (tid < 128) red[tid] = 0.f;
    if (tid < 32) sgns[tid] = (gb[tid] >= 0.f) ? 1.f : -1.f;
    __syncthreads();
    int g = tid & 3, cg = g*8;
    int r = (blockIdx.x*256 + tid) >> 2;
    int b = r >> 14, n = r & (NN-1);
    const int4* nb4 = (const int4*)(ei + (size_t)b*2*EE + EE + n*KK);
    int4 q0v = nb4[0], q1v = nb4[1];
    int nbr[KK] = {q0v.x,q0v.y,q0v.z,q0v.w,q1v.x,q1v.y,q1v.z,q1v.w};
    const float4* pc = (const float4*)(xf + (size_t)r*8);
    float4 c0 = pc[0], c1 = pc[1];
    float xv[8] = {c0.x,c0.y,c0.z,c0.w,c1.x,c1.y,c1.z,c1.w};
    float sgn[8];
#pragma unroll
    for (int j = 0; j < 8; ++j) sgn[j] = sgns[cg+j];

    // preload all 8 neighbor rows (keeps 16 loads in flight)
    float4 nA[KK], nB[KK];
#pragma unroll
    for (int k = 0; k < KK; ++k) {
        const float4* pn = (const float4*)(xf + ((size_t)(b<<14) + nbr[k])*8);
        nA[k] = pn[0]; nB[k] = pn[1];
    }

    // a-branch: this lane's 8 cols
    float opa[8];
#pragma unroll
    for (int j = 0; j < 8; ++j) {
        float s = 0.f;
#pragma unroll
        for (int k = 0; k < 8; ++k) s = fmaf(xv[k], wa[k*32+cg+j], s);
        opa[j] = s;
    }
    {
        ushort8v h;
#pragma unroll
        for (int j = 0; j < 8; ++j) h[j] = f2h(opa[j]);
        *(ushort8v*)&xa[(size_t)r*32 + cg] = h;
    }

    // b-branch over the 8 edges
    float s8[8], q8[8], mx[8];
#pragma unroll
    for (int j = 0; j < 8; ++j) { s8[j] = 0.f; q8[j] = 0.f; mx[j] = -3.0e38f; }
#pragma unroll
    for (int k = 0; k < KK; ++k) {
        float4 n0 = nA[k], n1 = nB[k];
        float d[8] = {n0.x-xv[0], n0.y-xv[1], n0.z-xv[2], n0.w-xv[3],
                      n1.x-xv[4], n1.y-xv[5], n1.z-xv[6], n1.w-xv[7]};
#pragma unroll
        for (int jj = 0; jj < 8; ++jj) {
            float z = 0.f;
#pragma unroll
            for (int k2 = 0; k2 < 8; ++k2) z = fmaf(d[k2], wb[k2*32+cg+jj], z);
            s8[jj] += z;
            q8[jj] = fmaf(z, z, q8[jj]);
            mx[jj] = fmaxf(mx[jj], sgn[jj]*z);
        }
    }
    // write sign-folded max (fp32, 32B/lane, 128B contiguous per center)
    {
        float4* mp = (float4*)&mxb[(size_t)r*32 + cg];
        mp[0] = (float4){mx[0],mx[1],mx[2],mx[3]};
        mp[1] = (float4){mx[4],mx[5],mx[6],mx[7]};
    }
    // stats: a uses opa (one per row), b uses s8/q8 (8 edges per row).
    float sa8[8], qa8[8];
#pragma unroll
    for (int j = 0; j < 8; ++j) { sa8[j] = opa[j]; qa8[j] = opa[j]*opa[j]; }
#pragma unroll
    for (int off = 4; off <= 32; off <<= 1) {
#pragma unroll
        for (int j = 0; j < 8; ++j) {
            s8[j]  += __shfl_xor(s8[j],  off, 64);
            q8[j]  += __shfl_xor(q8[j],  off, 64);
            sa8[j] += __shfl_xor(sa8[j], off, 64);
            qa8[j] += __shfl_xor(qa8[j], off, 64);
        }
    }
    if ((tid & 63) < 4) {
#pragma unroll
        for (int j = 0; j < 8; ++j) {
            atomicAdd(&red[cg + j],       sa8[j]);
            atomicAdd(&red[32 + cg + j],  qa8[j]);
            atomicAdd(&red[64 + cg + j],  s8[j]);
            atomicAdd(&red[96 + cg + j],  q8[j]);
        }
    }
    __syncthreads();
    size_t pl = (size_t)(blockIdx.x & (SPL-1))*512;
    if (tid < 64) atomicAdd(&Sa[pl + tid], red[tid]);
    else if (tid < 128) atomicAdd(&Sb[pl + (tid - 64)], red[tid]);
}

// ---- layer 0 apply (pure streaming): BN finalize + BNa+lrelu + BNb+lrelu(mx)
// + add -> x0 fp16, plus zc[r] = dot(x0_final, Wc[0:32]). No gathers. ----
__global__ __launch_bounds__(256) void k_edge_apply2(const float* __restrict__ mxb,
                                                     const float* __restrict__ Sa,
                                                     const float* __restrict__ Sb,
                                                     const float* __restrict__ ga,
                                                     const float* __restrict__ ba,
                                                     const float* __restrict__ gb,
                                                     const float* __restrict__ bbp,
                                                     const float* __restrict__ Wc,
                                                     unsigned short* __restrict__ x0,
                                                     float* __restrict__ zc) {
    __shared__ float scbA[32], shb[32], sca[32], sha[32], swc[32];
    int tid = threadIdx.x;
    if (tid < 32) {
        float su = 0.f, qu = 0.f;
        for (int p = 0; p < SPL; ++p) { su += Sa[(size_t)p*512 + tid]; qu += Sa[(size_t)p*512 + 32 + tid]; }
        float m = su*(1.f/RR);
        float v = fmaxf(qu*(1.f/RR) - m*m, 0.f);
        float sc = ga[tid]*rsqrtf(v + 1e-5f);
        sca[tid] = sc; sha[tid] = fmaf(-m, sc, ba[tid]);
        swc[tid] = Wc[tid];
    } else if (tid < 64) {
        int c = tid - 32;
        float su = 0.f, qu = 0.f;
        for (int p = 0; p < SPL; ++p) { su += Sb[(size_t)p*512 + c]; qu += Sb[(size_t)p*512 + 32 + c]; }
        float m = su*(1.f/EG);
        float v = fmaxf(qu*(1.f/EG) - m*m, 0.f);
        float sc = gb[c]*rsqrtf(v + 1e-5f);
        scbA[c] = fabsf(sc);
        shb[c] = fmaf(-m, sc, bbp[c]);
    }
    __syncthreads();
    int r = blockIdx.x*256 + tid;
    ushort8v* xp = (ushort8v*)(x0 + (size_t)r*32);
    const float4* mp = (const float4*)(mxb + (size_t)r*32);
    float sdot = 0.f;
#pragma unroll
    for (int i = 0; i < 4; ++i) {
        ushort8v v = xp[i];
        float4 m0 = mp[i*2], m1 = mp[i*2+1];
        float mx8[8] = {m0.x,m0.y,m0.z,m0.w,m1.x,m1.y,m1.z,m1.w};
        ushort8v o;
#pragma unroll
        for (int j = 0; j < 8; ++j) {
            int c = i*8 + j;
            float y = lrelu(fmaf(mx8[j], scbA[c], shb[c]));
            float val = lrelu(fmaf(h2f(v[j]), sca[c], sha[c])) + y;
            o[j] = f2h(val);
            sdot = fmaf(val, swc[c], sdot);
        }
        xp[i] = o;
    }
    zc[r] = sdot;
}

// ---- fused prep: zero stats + pack W1/W2/W3 into MFMA fragment order (1 launch) ----
template<int CI, int CO>
__device__ __forceinline__ void packone(int t, const float* __restrict__ Wa,
                                        const float* __restrict__ Wb,
                                        unsigned short* __restrict__ Wp) {
    constexpr int NT = 2*CO;
    constexpr int KT = CI/32;
    int ng = t % NT, k = t / NT;
    float v = (ng < CO) ? Wa[(size_t)k*CO + ng] : Wb[(size_t)k*CO + (ng - CO)];
    int nt = ng >> 4, n = ng & 15;
    int kt = k >> 5, kq = (k & 31) >> 3, j = k & 7;
    int f = nt*KT + kt;
    int idx = f*512 + ((kq*16 + n)<<3) + j;
    Wp[idx] = f2h(v);
}

__global__ __launch_bounds__(256) void k_prep(const float* __restrict__ W1a, const float* __restrict__ W1b,
                                              const float* __restrict__ W2a, const float* __restrict__ W2b,
                                              const float* __restrict__ W3a, const float* __restrict__ W3b,
                                              unsigned short* __restrict__ wp1,
                                              unsigned short* __restrict__ wp2,
                                              unsigned short* __restrict__ wp3,
                                              float* __restrict__ S) {
    int t = blockIdx.x*256 + threadIdx.x;
    int NT_ = gridDim.x*256;
    for (int u = t; u < (int)(9*SLOT); u += NT_) S[u] = 0.f;
    for (int u = t; u < 32*128;  u += NT_) packone<32,64>(u, W1a, W1b, wp1);
    for (int u = t; u < 64*256;  u += NT_) packone<64,128>(u, W2a, W2b, wp2);
    for (int u = t; u < 128*512; u += NT_) packone<128,256>(u, W3a, W3b, wp3);
}

// ---- dual MFMA GEMM v5 (register-resident W, no LDS in main loop, no
// __syncthreads, NO device fences — per-block __threadfence on CDNA forces
// an XCD L2 writeback and was a 2x regression; stats fold stays a separate
// tiny launch). Scheduling per KT:
//   KT==1 (L1): 2 tiles/wave, both X loads issued up front.
//   KT==2 (L2): distance-1 ping-pong across kt-steps and tiles.
//   KT==4 (L3): 4 X buffers, distance-2 prefetch, phase-stable.
template<int CI, int CO, int MW>
__global__ __launch_bounds__(256, MW) void k_mfma_dual4(const unsigned short* __restrict__ X,
                                                        const unsigned short* __restrict__ Wp,
                                                        unsigned short* __restrict__ Za,
                                                        unsigned short* __restrict__ Zb,
                                                        float* __restrict__ Sa,
                                                        float* __restrict__ Sb) {
    constexpr int NCH = 4;
    constexpr int KT = CI/32;
    constexpr int WCNT = NCH*KT*512;
    constexpr int ROWT = RR/64;
    constexpr int STR = NCH*16 + 8;
    constexpr int XW  = (CI < 64) ? CI : 64;
    constexpr int PLB = CO/64;
    __shared__ unsigned short scr[4][16*STR];
    int tid = threadIdx.x;
    int lane = tid & 63, wid = tid >> 6;
    int ch = blockIdx.y;
    int wglob = blockIdx.x*4 + wid;
    int NW = gridDim.x*4;
    int n = lane & 15, kq = lane >> 4;
    int rg = lane >> 3, c8l = (lane & 7)*8;
    unsigned short* myscr = scr[wid];
    size_t pl = (size_t)(wglob & (SPL-1)) * 512;
    bool isA = (ch < PLB);
    unsigned short* Zp = (isA ? Za : Zb) + (size_t)(isA ? ch : ch - PLB)*((size_t)RR*64);

    // W direct from global (L2-resident, coalesced 16B/lane) into registers
    half8v wreg[KT][NCH];
    {
        const unsigned short* Wc = Wp + (size_t)ch*WCNT;
#pragma unroll
        for (int kt = 0; kt < KT; ++kt)
#pragma unroll
            for (int j = 0; j < NCH; ++j)
                wreg[kt][j] = *(const half8v*)&Wc[(j*KT + kt)*512 + lane*8];
    }

    float4v ps[NCH], pq[NCH];
#pragma unroll
    for (int j = 0; j < NCH; ++j) { ps[j] = (float4v){0,0,0,0}; pq[j] = (float4v){0,0,0,0}; }

    auto issue = [&](half8v (&dst)[4], size_t rowb, int kt) {
        int k0 = kt*32 + kq*8;
        int xpl = k0 >> 6;
        int xoff = k0 & (XW-1);
        const unsigned short* Xp = X + (size_t)xpl*((size_t)RR*64);
#pragma unroll
        for (int i = 0; i < 4; ++i)
            dst[i] = *(const half8v*)&Xp[(rowb + i*16 + n)*XW + xoff];
    };

    auto domfma = [&](float4v (&acc)[4][NCH], half8v (&wk)[NCH], half8v (&bc)[4]) {
#pragma unroll
        for (int j = 0; j < NCH; ++j)
#pragma unroll
            for (int i = 0; i < 4; ++i)
                acc[i][j] = __builtin_amdgcn_mfma_f32_16x16x32_f16(wk[j], bc[i], acc[i][j], 0, 0, 0);
    };

    auto epilogue = [&](float4v (&acc)[4][NCH], size_t rowbase) {
#pragma unroll
        for (int j = 0; j < NCH; ++j)
#pragma unroll
            for (int i = 0; i < 4; ++i) {
                float4v a4 = acc[i][j];
#pragma unroll
                for (int reg = 0; reg < 4; ++reg) {
                    ps[j][reg] += a4[reg];
                    pq[j][reg] = fmaf(a4[reg], a4[reg], pq[j][reg]);
                }
            }
#pragma unroll
        for (int i = 0; i < 4; ++i) {
            __builtin_amdgcn_wave_barrier();
#pragma unroll
            for (int j = 0; j < NCH; ++j) {
                float4v a4 = acc[i][j];
                ushort4 h = { f2h(a4[0]), f2h(a4[1]), f2h(a4[2]), f2h(a4[3]) };
                *(ushort4*)&myscr[n*STR + j*16 + kq*4] = h;
            }
            __builtin_amdgcn_wave_barrier();
#pragma unroll
            for (int i2 = 0; i2 < 2; ++i2) {
                int rit = rg + i2*8;
                ushort8v v = *(const ushort8v*)&myscr[rit*STR + c8l];
                *(ushort8v*)&Zp[(rowbase + i*16 + rit)*64 + c8l] = v;
            }
        }
    };

    if constexpr (KT == 1) {
        half8v b0[4], b1[4];
        for (int t = wglob; t < ROWT; t += 2*NW) {
            int tB = t + NW;
            size_t rbA = (size_t)t*64;
            issue(b0, rbA, 0);
            bool hasB = (tB < ROWT);
            size_t rbB = hasB ? (size_t)tB*64 : rbA;
            if (hasB) issue(b1, rbB, 0);
            {
                float4v acc[4][NCH];
#pragma unroll
                for (int i = 0; i < 4; ++i)
#pragma unroll
                    for (int j = 0; j < NCH; ++j) acc[i][j] = (float4v){0,0,0,0};
                domfma(acc, wreg[0], b0);
                epilogue(acc, rbA);
            }
            if (hasB) {
                float4v acc[4][NCH];
#pragma unroll
                for (int i = 0; i < 4; ++i)
#pragma unroll
                    for (int j = 0; j < NCH; ++j) acc[i][j] = (float4v){0,0,0,0};
                domfma(acc, wreg[0], b1);
                epilogue(acc, rbB);
            }
        }
    } else if constexpr (KT == 4) {
        half8v p0[4], p1[4], p2[4], p3[4];
        int t = wglob;
        if (t < ROWT) {
            issue(p0, (size_t)t*64, 0);
            issue(p1, (size_t)t*64, 1);
        }
        for (; t < ROWT; t += NW) {
            size_t rowbase = (size_t)t*64;
            int t2 = t + NW;
            size_t nextrb = (t2 < ROWT) ? (size_t)t2*64 : rowbase;
            float4v acc[4][NCH];
#pragma unroll
            for (int i = 0; i < 4; ++i)
#pragma unroll
                for (int j = 0; j < NCH; ++j) acc[i][j] = (float4v){0,0,0,0};
            issue(p2, rowbase, 2);  domfma(acc, wreg[0], p0);
            issue(p3, rowbase, 3);  domfma(acc, wreg[1], p1);
            issue(p0, nextrb, 0);   domfma(acc, wreg[2], p2);
            issue(p1, nextrb, 1);   domfma(acc, wreg[3], p3);
            epilogue(acc, rowbase);
        }
    } else {
        half8v b0[4], b1[4];
        int t = wglob;
        if (t < ROWT) issue(b0, (size_t)t*64, 0);
        for (; t < ROWT; t += NW) {
            size_t rowbase = (size_t)t*64;
            int t2 = t + NW;
            size_t nextrb = (t2 < ROWT) ? (size_t)t2*64 : rowbase;
            float4v acc[4][NCH];
#pragma unroll
            for (int i = 0; i < 4; ++i)
#pragma unroll
                for (int j = 0; j < NCH; ++j) acc[i][j] = (float4v){0,0,0,0};
            issue(b1, rowbase, 1);  domfma(acc, wreg[0], b0);
            issue(b0, nextrb, 0);   domfma(acc, wreg[1], b1);
            epilogue(acc, rowbase);
        }
    }

    {
        float* Sg = isA ? Sa : Sb;
        int cb0 = isA ? ch*64 : ch*64 - CO;
#pragma unroll
        for (int j = 0; j < NCH; ++j) {
#pragma unroll
            for (int reg = 0; reg < 4; ++reg) {
                float s = ps[j][reg], q = pq[j][reg];
                s += __shfl_xor(s, 1, 64); q += __shfl_xor(q, 1, 64);
                s += __shfl_xor(s, 2, 64); q += __shfl_xor(q, 2, 64);
                s += __shfl_xor(s, 4, 64); q += __shfl_xor(q, 4, 64);
                s += __shfl_xor(s, 8, 64); q += __shfl_xor(q, 8, 64);
                if (n == 0) {
                    int col = cb0 + j*16 + kq*4 + reg;
                    atomicAdd(&Sg[pl + col], s);
                    atomicAdd(&Sg[pl + CO + col], q);
                }
            }
        }
    }
}

// ---- fold 64 stat planes into plane 0 for both BN slots of a layer.
// Wave-per-column: 64 lanes each read one plane, shfl-xor tree reduce.
// Critical path: 1 load + 6 shuffles (was 63 serial accumulating loads). ----
template<int CO>
__global__ __launch_bounds__(256) void k_redstats(float* __restrict__ Sa,
                                                  float* __restrict__ Sb) {
    int tid = threadIdx.x;
    int lane = tid & 63;
    int wv = blockIdx.x*4 + (tid >> 6);   // global wave index
    int total = 4*CO;                     // Sa: 2*CO entries, Sb: 2*CO entries
    if (wv >= total) return;
    bool isB = (wv >= 2*CO);
    int u = isB ? (wv - 2*CO) : wv;
    float* Sg = isB ? Sb : Sa;
    float v = Sg[(size_t)lane*512 + u];   // lane = plane index (SPL == 64)
#pragma unroll
    for (int off = 32; off >= 1; off >>= 1) v += __shfl_xor(v, off, 64);
    if (lane == 0) Sg[u] = v;
}

// ---- fused: BN finalize + BNa+lrelu center + gather-max(BNb+lrelu) + add
// + cat contribution. Packed-fp16 sign-folded max. (plane,batch)-combo block
// mapping pins each gather slab (2MB) to one XCD. (Nontemporal hints on the
// streaming accesses were tested and slightly REGRESSED — nt stores defeat
// reuse of x-writeback lines by the next layer's GEMM; reverted.)
// WRITEBACK=false for the last layer (x3 dead after the cat dot).
template<int CO, bool WRITEBACK>
__global__ __launch_bounds__(256) void k_gathermax(unsigned short* __restrict__ xi,
                                                   const unsigned short* __restrict__ zbh,
                                                   const int* __restrict__ ei,
                                                   const float* __restrict__ Sa,
                                                   const float* __restrict__ Sb,
                                                   const float* __restrict__ ga,
                                                   const float* __restrict__ ba,
                                                   const float* __restrict__ gb,
                                                   const float* __restrict__ bbp,
                                                   const float* __restrict__ Wc,
                                                   int wcoff,
                                                   float* __restrict__ zc) {
    constexpr int P = CO/64;                 // planes
    __shared__ float sca[CO], sha[CO], sbA[CO], shb[CO], swc[CO];
    __shared__ __attribute__((aligned(16))) unsigned short smk[CO];
    int tid = threadIdx.x;
    for (int u = tid; u < CO; u += 256) {
        float m = Sa[u]*(1.f/RR);
        float v = fmaxf(Sa[CO+u]*(1.f/RR) - m*m, 0.f);
        float sc = ga[u]*rsqrtf(v + 1e-5f);
        sca[u] = sc; sha[u] = fmaf(-m, sc, ba[u]);
        m = Sb[u]*(1.f/RR);
        v = fmaxf(Sb[CO+u]*(1.f/RR) - m*m, 0.f);
        sc = gb[u]*rsqrtf(v + 1e-5f);
        sbA[u] = fabsf(sc);
        smk[u] = (sc >= 0.f) ? (unsigned short)0 : (unsigned short)0x8000;
        shb[u] = fmaf(-m, sc, bbp[u]);
        swc[u] = Wc[wcoff + u];
    }
    __syncthreads();
    // (plane,batch)-combo partitioning, combos pinned to XCDs (bx & 7)
    int bx = blockIdx.x;
    int xcd = bx & 7;
    int idx = bx >> 3;
    int combo, inner;
    if constexpr (P == 4) {        // 16 combos, grid 8192: 2 combos per XCD
        combo = xcd*2 + (idx >> 9);
        inner = idx & 511;
    } else if constexpr (P == 2) { // 8 combos, grid 4096: 1 combo per XCD
        combo = xcd;
        inner = idx;
    } else {                       // 4 combos, grid 2048: 2 XCDs per combo
        combo = xcd >> 1;
        inner = (idx << 1) | (xcd & 1);
    }
    int pln = combo >> 2;          // combo = pln*BB + b
    int b   = combo & 3;
    int t = inner*256 + tid;       // 0..131071 within combo
    int n = t >> 3;
    int sub = t & 7;
    int c8 = pln*64 + sub*8;
    int off = sub*8;
    int r = (b << 14) | n;
    const unsigned short* zpl = zbh + (size_t)pln*((size_t)RR*64);
    unsigned short* xpl = xi + (size_t)pln*((size_t)RR*64);
    const int4* nb4 = (const int4*)(ei + (size_t)b*2*EE + EE + n*KK);
    int4 q0 = nb4[0], q1 = nb4[1];
    int nbr[KK] = {q0.x,q0.y,q0.z,q0.w,q1.x,q1.y,q1.z,q1.w};
    size_t bb64 = ((size_t)(b<<14))*64 + off;
    ushort8v* xp = (ushort8v*)&xpl[(size_t)r*64 + off];
    ushort8v a = *xp;
    ushort8v u[KK];
#pragma unroll
    for (int k = 0; k < KK; ++k)
        u[k] = *(const ushort8v*)(zpl + bb64 + (size_t)nbr[k]*64);
    // packed fp16 sign-folded max
    ushort8v msk8 = *(const ushort8v*)&smk[c8];
    ushort8v ninfu = {0xFC00,0xFC00,0xFC00,0xFC00,0xFC00,0xFC00,0xFC00,0xFC00};
    half8v mh = __builtin_bit_cast(half8v, ninfu);
#pragma unroll
    for (int k = 0; k < KK; ++k) {
        ushort8v uk = u[k] ^ msk8;
        mh = h8max(mh, __builtin_bit_cast(half8v, uk));
    }
    float sb[8], hb[8];
#pragma unroll
    for (int j = 0; j < 8; ++j) { sb[j] = sbA[c8+j]; hb[j] = shb[c8+j]; }
    float sdot = 0.f;
    if (WRITEBACK) {
        ushort8v o;
#pragma unroll
        for (int j = 0; j < 8; ++j) {
            int c = c8 + j;
            float y = lrelu(fmaf((float)mh[j], sb[j], hb[j]));
            float val = lrelu(fmaf(h2f(a[j]), sca[c], sha[c])) + y;
            o[j] = f2h(val);
            sdot = fmaf(val, swc[c], sdot);
        }
        *xp = o;
    } else {
#pragma unroll
        for (int j = 0; j < 8; ++j) {
            int c = c8 + j;
            float y = lrelu(fmaf((float)mh[j], sb[j], hb[j]));
            float val = lrelu(fmaf(h2f(a[j]), sca[c], sha[c])) + y;
            sdot = fmaf(val, swc[c], sdot);
        }
    }
    // reduce the 8 sub-lanes of this row (contiguous lanes)
    sdot += __shfl_xor(sdot, 1, 64);
    sdot += __shfl_xor(sdot, 2, 64);
    sdot += __shfl_xor(sdot, 4, 64);
    if (sub == 0) atomicAdd(&zc[r], sdot);
}

// ---- cat head (single kernel, replaces catstats+catfinal): each block
// redundantly reduces the full zc array (256KB, LLC-hot, float4-vectorized —
// identical order in every block so the BN constants are deterministic and
// consistent), then applies BN(1 col) + leaky + bias to its own 256 rows.
// 256 blocks x 262KB = 67MB of L2/L3 reads ~= 2us aggregate; saves one
// launch + gap + the S8 atomic round-trip. ----
__global__ __launch_bounds__(256) void k_cat(const float* __restrict__ zc,
                                             const float* __restrict__ g,
                                             const float* __restrict__ bb,
                                             const float* __restrict__ bias,
                                             float* __restrict__ out) {
    __shared__ float rs[4], rq[4];
    int tid = threadIdx.x;
    const float4* z4 = (const float4*)zc;
    float s = 0.f, q = 0.f;
    for (int i = tid; i < RR/4; i += 256) {
        float4 v = z4[i];
        s += (v.x + v.y) + (v.z + v.w);
        q = fmaf(v.x, v.x, fmaf(v.y, v.y, fmaf(v.z, v.z, fmaf(v.w, v.w, q))));
    }
#pragma unroll
    for (int off = 32; off >= 1; off >>= 1) {
        s += __shfl_xor(s, off, 64);
        q += __shfl_xor(q, off, 64);
    }
    if ((tid & 63) == 0) { rs[tid >> 6] = s; rq[tid >> 6] = q; }
    __syncthreads();
    float st = (rs[0] + rs[1]) + (rs[2] + rs[3]);
    float qt = (rq[0] + rq[1]) + (rq[2] + rq[3]);
    const float invR = 1.f/65536.f;
    float m = st*invR;
    float v = fmaxf(qt*invR - m*m, 0.f);
    float sc = g[0]*rsqrtf(v + 1e-5f);
    float sh = fmaf(-m, sc, bb[0]);
    int r = blockIdx.x*256 + tid;
    out[r] = lrelu(fmaf(zc[r], sc, sh)) + bias[0];
}

extern "C" void kernel_launch(void* const* d_in, const int* in_sizes, int n_in,
                              void* d_out, int out_size, void* d_ws, size_t ws_size,
                              hipStream_t stream) {
    const float* x    = (const float*)d_in[0];
    const int*   ei   = (const int*)d_in[1];
    const float* W0a  = (const float*)d_in[2];
    const float* g0a  = (const float*)d_in[3];
    const float* b0a  = (const float*)d_in[4];
    const float* W0b  = (const float*)d_in[5];
    const float* g0b  = (const float*)d_in[6];
    const float* b0b  = (const float*)d_in[7];
    const float* W1a  = (const float*)d_in[8];
    const float* g1a  = (const float*)d_in[9];
    const float* b1a  = (const float*)d_in[10];
    const float* W1b  = (const float*)d_in[11];
    const float* g1b  = (const float*)d_in[12];
    const float* b1b  = (const float*)d_in[13];
    const float* W2a  = (const float*)d_in[14];
    const float* g2a  = (const float*)d_in[15];
    const float* b2a  = (const float*)d_in[16];
    const float* W2b  = (const float*)d_in[17];
    const float* g2b  = (const float*)d_in[18];
    const float* b2b  = (const float*)d_in[19];
    const float* W3a  = (const float*)d_in[20];
    const float* g3a  = (const float*)d_in[21];
    const float* b3a  = (const float*)d_in[22];
    const float* W3b  = (const float*)d_in[23];
    const float* g3b  = (const float*)d_in[24];
    const float* b3b  = (const float*)d_in[25];
    const float* Wcat = (const float*)d_in[26];
    const float* gcat = (const float*)d_in[27];
    const float* bcat = (const float*)d_in[28];
    const float* bias = (const float*)d_in[29];
    float* out = (float*)d_out;

    float* ws = (float*)d_ws;
    unsigned short* x0 = (unsigned short*)(ws + OFF_X0);
    unsigned short* x1 = (unsigned short*)(ws + OFF_X1);
    unsigned short* x2 = (unsigned short*)(ws + OFF_X2);
    unsigned short* x3 = (unsigned short*)(ws + OFF_X3);
    unsigned short* zbh = (unsigned short*)(ws + OFF_ZB);
    float* zc = ws + OFF_ZC;
    float* S  = ws + OFF_S;
    unsigned short* wpbase = (unsigned short*)(ws + OFF_WP);
    unsigned short* wp1 = wpbase + WP1_OFF;
    unsigned short* wp2 = wpbase + WP2_OFF;
    unsigned short* wp3 = wpbase + WP3_OFF;
    float* mxb = ws + OFF_MX;
    auto Sl = [&](int i) { return S + (size_t)i*SLOT; };

    // ---- fused weight prep + stats zero ----
    k_prep<<<256, 256, 0, stream>>>(W1a, W1b, W2a, W2b, W3a, W3b, wp1, wp2, wp3, S);

    // ---- layer 0: fused single-gather-pass, then streaming finalize ----
    k_l0_fused<<<RR*4/256, 256, 0, stream>>>(x, ei, W0a, W0b, g0b, x0, mxb, Sl(0), Sl(1));
    k_edge_apply2<<<RR/256, 256, 0, stream>>>(mxb, Sl(0), Sl(1),
                                              g0a, b0a, g0b, b0b, Wcat, x0, zc);

    // ---- layer 1: 32 -> 64 (reg-W, 2 tiles/wave pipelined) ----
    k_mfma_dual4<32,64,3><<<dim3(128,2), 256, 0, stream>>>(x0, wp1, x1, zbh, Sl(2), Sl(3));
    k_redstats<64><<<64, 256, 0, stream>>>(Sl(2), Sl(3));
    k_gathermax<64,true><<<RR*8/256, 256, 0, stream>>>(x1, zbh, ei, Sl(2), Sl(3),
                                                       g1a, b1a, g1b, b1b, Wcat, 32, zc);

    // ---- layer 2: 64 -> 128 (reg-W, distance-1 ping-pong) ----
    k_mfma_dual4<64,128,3><<<dim3(128,4), 256, 0, stream>>>(x1, wp2, x2, zbh, Sl(4), Sl(5));
    k_redstats<128><<<128, 256, 0, stream>>>(Sl(4), Sl(5));
    k_gathermax<128,true><<<RR*16/256, 256, 0, stream>>>(x2, zbh, ei, Sl(4), Sl(5),
                                                         g2a, b2a, g2b, b2b, Wcat, 96, zc);

    // ---- layer 3: 128 -> 256 (reg-W, distance-2 prefetch, 4 tiles/wave) ----
    k_mfma_dual4<128,256,2><<<dim3(64,8), 256, 0, stream>>>(x2, wp3, x3, zbh, Sl(6), Sl(7));
    k_redstats<256><<<256, 256, 0, stream>>>(Sl(6), Sl(7));
    k_gathermax<256,false><<<RR*32/256, 256, 0, stream>>>(x3, zbh, ei, Sl(6), Sl(7),
                                                          g3a, b3a, g3b, b3b, Wcat, 224, zc);

    // ---- cat head (single fused kernel) ----
    k_cat<<<RR/256, 256, 0, stream>>>(zc, gcat, bcat, bias, out);
}

// Round 12
// 266.948 us; speedup vs baseline: 1.0558x; 1.0558x over previous
//
#include <hip/hip_runtime.h>
#include <math.h>

// Problem constants
static constexpr int BB = 4;
static constexpr int NN = 16384;
static constexpr int KK = 8;
static constexpr int EE = 131072;   // edges per batch
static constexpr int RR = 65536;    // BB*NN rows
static constexpr int EG = 524288;   // total edges

// Stats: 64 planes x 512 floats per BN slot
static constexpr int SPL = 64;
static constexpr size_t SLOT = (size_t)SPL*512;

// Workspace layout (float offsets)
static constexpr size_t OFF_X0 = 0;
static constexpr size_t OFF_X1 = OFF_X0 + (size_t)RR*32;
static constexpr size_t OFF_X2 = OFF_X1 + (size_t)RR*64;
static constexpr size_t OFF_X3 = OFF_X2 + (size_t)RR*128;
static constexpr size_t OFF_ZB = OFF_X3 + (size_t)RR*256; // fp16 b-branch
static constexpr size_t OFF_ZC = OFF_ZB + (size_t)RR*128; // 65536 fp32
static constexpr size_t OFF_S  = OFF_ZC + (size_t)RR;     // 9 slots * SLOT
static constexpr size_t OFF_WP = OFF_S + 9*SLOT;          // packed fp16 weights
static constexpr size_t OFF_MX = OFF_WP + 65536;          // layer-0 edge max (RR*32 fp32)
static constexpr size_t WP1_OFF = 0;
static constexpr size_t WP2_OFF = 4096;
static constexpr size_t WP3_OFF = 4096 + 16384;

__device__ __forceinline__ float lrelu(float x) { return fmaxf(x, 0.2f*x); }

__device__ __forceinline__ unsigned short f2h(float f) {
    _Float16 h = (_Float16)f;
    return *(unsigned short*)&h;
}
__device__ __forceinline__ float h2f(unsigned short u) {
    _Float16 h = *(_Float16*)&u;
    return (float)h;
}

typedef __attribute__((ext_vector_type(8))) _Float16 half8v;
typedef __attribute__((ext_vector_type(8))) unsigned short ushort8v;
typedef __attribute__((ext_vector_type(4))) float float4v;

// packed fp16 elementwise max (v_pk_max_f16); fp16 compare is exact, so the
// gather-max computed in fp16 over fp16 data is bit-identical to the f32 path.
__device__ __forceinline__ half8v h8max(half8v a, half8v b) {
#if __has_builtin(__builtin_elementwise_max)
    return __builtin_elementwise_max(a, b);
#else
    half8v r;
#pragma unroll
    for (int j = 0; j < 8; ++j) r[j] = (a[j] > b[j]) ? a[j] : b[j];
    return r;
#endif
}

// ---- layer 0 FUSED: a-branch GEMM 8->32 (pre-BN fp16 out) + a-stats +
// b-branch edge MLP over each center's 8 edges computing b-stats AND the
// sign-folded per-center max in ONE gather pass. Quad-split: 4 lanes per
// center, 8 cols each. Neighbor rows preloaded to regs for latency overlap.
__global__ __launch_bounds__(256) void k_l0_fused(const float* __restrict__ xf,
                                                  const int* __restrict__ ei,
                                                  const float* __restrict__ Wa,
                                                  const float* __restrict__ Wb,
                                                  const float* __restrict__ gb,
                                                  unsigned short* __restrict__ xa,
                                                  float* __restrict__ mxb,
                                                  float* __restrict__ Sa,
                                                  float* __restrict__ Sb) {
    __shared__ float wa[256], wb[256];
    __shared__ float red[128];
    __shared__ float sgns[32];
    int tid = threadIdx.x;
    wa[tid] = Wa[tid];
    wb[tid] = Wb[tid];
    if (tid < 128) red[tid] = 0.f;
    if (tid < 32) sgns[tid] = (gb[tid] >= 0.f) ? 1.f : -1.f;
    __syncthreads();
    int g = tid & 3, cg = g*8;
    int r = (blockIdx.x*256 + tid) >> 2;
    int b = r >> 14, n = r & (NN-1);
    const int4* nb4 = (const int4*)(ei + (size_t)b*2*EE + EE + n*KK);
    int4 q0v = nb4[0], q1v = nb4[1];
    int nbr[KK] = {q0v.x,q0v.y,q0v.z,q0v.w,q1v.x,q1v.y,q1v.z,q1v.w};
    const float4* pc = (const float4*)(xf + (size_t)r*8);
    float4 c0 = pc[0], c1 = pc[1];
    float xv[8] = {c0.x,c0.y,c0.z,c0.w,c1.x,c1.y,c1.z,c1.w};
    float sgn[8];
#pragma unroll
    for (int j = 0; j < 8; ++j) sgn[j] = sgns[cg+j];

    // preload all 8 neighbor rows (keeps 16 loads in flight)
    float4 nA[KK], nB[KK];
#pragma unroll
    for (int k = 0; k < KK; ++k) {
        const float4* pn = (const float4*)(xf + ((size_t)(b<<14) + nbr[k])*8);
        nA[k] = pn[0]; nB[k] = pn[1];
    }

    // a-branch: this lane's 8 cols
    float opa[8];
#pragma unroll
    for (int j = 0; j < 8; ++j) {
        float s = 0.f;
#pragma unroll
        for (int k = 0; k < 8; ++k) s = fmaf(xv[k], wa[k*32+cg+j], s);
        opa[j] = s;
    }
    {
        ushort8v h;
#pragma unroll
        for (int j = 0; j < 8; ++j) h[j] = f2h(opa[j]);
        *(ushort8v*)&xa[(size_t)r*32 + cg] = h;
    }

    // b-branch over the 8 edges
    float s8[8], q8[8], mx[8];
#pragma unroll
    for (int j = 0; j < 8; ++j) { s8[j] = 0.f; q8[j] = 0.f; mx[j] = -3.0e38f; }
#pragma unroll
    for (int k = 0; k < KK; ++k) {
        float4 n0 = nA[k], n1 = nB[k];
        float d[8] = {n0.x-xv[0], n0.y-xv[1], n0.z-xv[2], n0.w-xv[3],
                      n1.x-xv[4], n1.y-xv[5], n1.z-xv[6], n1.w-xv[7]};
#pragma unroll
        for (int jj = 0; jj < 8; ++jj) {
            float z = 0.f;
#pragma unroll
            for (int k2 = 0; k2 < 8; ++k2) z = fmaf(d[k2], wb[k2*32+cg+jj], z);
            s8[jj] += z;
            q8[jj] = fmaf(z, z, q8[jj]);
            mx[jj] = fmaxf(mx[jj], sgn[jj]*z);
        }
    }
    // write sign-folded max (fp32, 32B/lane, 128B contiguous per center)
    {
        float4* mp = (float4*)&mxb[(size_t)r*32 + cg];
        mp[0] = (float4){mx[0],mx[1],mx[2],mx[3]};
        mp[1] = (float4){mx[4],mx[5],mx[6],mx[7]};
    }
    // stats: a uses opa (one per row), b uses s8/q8 (8 edges per row).
    float sa8[8], qa8[8];
#pragma unroll
    for (int j = 0; j < 8; ++j) { sa8[j] = opa[j]; qa8[j] = opa[j]*opa[j]; }
#pragma unroll
    for (int off = 4; off <= 32; off <<= 1) {
#pragma unroll
        for (int j = 0; j < 8; ++j) {
            s8[j]  += __shfl_xor(s8[j],  off, 64);
            q8[j]  += __shfl_xor(q8[j],  off, 64);
            sa8[j] += __shfl_xor(sa8[j], off, 64);
            qa8[j] += __shfl_xor(qa8[j], off, 64);
        }
    }
    if ((tid & 63) < 4) {
#pragma unroll
        for (int j = 0; j < 8; ++j) {
            atomicAdd(&red[cg + j],       sa8[j]);
            atomicAdd(&red[32 + cg + j],  qa8[j]);
            atomicAdd(&red[64 + cg + j],  s8[j]);
            atomicAdd(&red[96 + cg + j],  q8[j]);
        }
    }
    __syncthreads();
    size_t pl = (size_t)(blockIdx.x & (SPL-1))*512;
    if (tid < 64) atomicAdd(&Sa[pl + tid], red[tid]);
    else if (tid < 128) atomicAdd(&Sb[pl + (tid - 64)], red[tid]);
}

// ---- layer 0 apply (pure streaming): BN finalize + BNa+lrelu + BNb+lrelu(mx)
// + add -> x0 fp16, plus zc[r] = dot(x0_final, Wc[0:32]). No gathers. ----
__global__ __launch_bounds__(256) void k_edge_apply2(const float* __restrict__ mxb,
                                                     const float* __restrict__ Sa,
                                                     const float* __restrict__ Sb,
                                                     const float* __restrict__ ga,
                                                     const float* __restrict__ ba,
                                                     const float* __restrict__ gb,
                                                     const float* __restrict__ bbp,
                                                     const float* __restrict__ Wc,
                                                     unsigned short* __restrict__ x0,
                                                     float* __restrict__ zc) {
    __shared__ float scbA[32], shb[32], sca[32], sha[32], swc[32];
    int tid = threadIdx.x;
    if (tid < 32) {
        float su = 0.f, qu = 0.f;
        for (int p = 0; p < SPL; ++p) { su += Sa[(size_t)p*512 + tid]; qu += Sa[(size_t)p*512 + 32 + tid]; }
        float m = su*(1.f/RR);
        float v = fmaxf(qu*(1.f/RR) - m*m, 0.f);
        float sc = ga[tid]*rsqrtf(v + 1e-5f);
        sca[tid] = sc; sha[tid] = fmaf(-m, sc, ba[tid]);
        swc[tid] = Wc[tid];
    } else if (tid < 64) {
        int c = tid - 32;
        float su = 0.f, qu = 0.f;
        for (int p = 0; p < SPL; ++p) { su += Sb[(size_t)p*512 + c]; qu += Sb[(size_t)p*512 + 32 + c]; }
        float m = su*(1.f/EG);
        float v = fmaxf(qu*(1.f/EG) - m*m, 0.f);
        float sc = gb[c]*rsqrtf(v + 1e-5f);
        scbA[c] = fabsf(sc);
        shb[c] = fmaf(-m, sc, bbp[c]);
    }
    __syncthreads();
    int r = blockIdx.x*256 + tid;
    ushort8v* xp = (ushort8v*)(x0 + (size_t)r*32);
    const float4* mp = (const float4*)(mxb + (size_t)r*32);
    float sdot = 0.f;
#pragma unroll
    for (int i = 0; i < 4; ++i) {
        ushort8v v = xp[i];
        float4 m0 = mp[i*2], m1 = mp[i*2+1];
        float mx8[8] = {m0.x,m0.y,m0.z,m0.w,m1.x,m1.y,m1.z,m1.w};
        ushort8v o;
#pragma unroll
        for (int j = 0; j < 8; ++j) {
            int c = i*8 + j;
            float y = lrelu(fmaf(mx8[j], scbA[c], shb[c]));
            float val = lrelu(fmaf(h2f(v[j]), sca[c], sha[c])) + y;
            o[j] = f2h(val);
            sdot = fmaf(val, swc[c], sdot);
        }
        xp[i] = o;
    }
    zc[r] = sdot;
}

// ---- fused prep: zero stats + pack W1/W2/W3 into MFMA fragment order (1 launch) ----
template<int CI, int CO>
__device__ __forceinline__ void packone(int t, const float* __restrict__ Wa,
                                        const float* __restrict__ Wb,
                                        unsigned short* __restrict__ Wp) {
    constexpr int NT = 2*CO;
    constexpr int KT = CI/32;
    int ng = t % NT, k = t / NT;
    float v = (ng < CO) ? Wa[(size_t)k*CO + ng] : Wb[(size_t)k*CO + (ng - CO)];
    int nt = ng >> 4, n = ng & 15;
    int kt = k >> 5, kq = (k & 31) >> 3, j = k & 7;
    int f = nt*KT + kt;
    int idx = f*512 + ((kq*16 + n)<<3) + j;
    Wp[idx] = f2h(v);
}

__global__ __launch_bounds__(256) void k_prep(const float* __restrict__ W1a, const float* __restrict__ W1b,
                                              const float* __restrict__ W2a, const float* __restrict__ W2b,
                                              const float* __restrict__ W3a, const float* __restrict__ W3b,
                                              unsigned short* __restrict__ wp1,
                                              unsigned short* __restrict__ wp2,
                                              unsigned short* __restrict__ wp3,
                                              float* __restrict__ S) {
    int t = blockIdx.x*256 + threadIdx.x;
    int NT_ = gridDim.x*256;
    for (int u = t; u < (int)(9*SLOT); u += NT_) S[u] = 0.f;
    for (int u = t; u < 32*128;  u += NT_) packone<32,64>(u, W1a, W1b, wp1);
    for (int u = t; u < 64*256;  u += NT_) packone<64,128>(u, W2a, W2b, wp2);
    for (int u = t; u < 128*512; u += NT_) packone<128,256>(u, W3a, W3b, wp3);
}

// ---- dual MFMA GEMM v5 (register-resident W, no LDS in main loop, no
// __syncthreads, NO device fences — per-block __threadfence on CDNA forces
// an XCD L2 writeback and was a 2x regression; stats fold stays a separate
// tiny launch). Scheduling per KT:
//   KT==1 (L1): 2 tiles/wave, both X loads issued up front.
//   KT==2 (L2): distance-1 ping-pong across kt-steps and tiles.
//   KT==4 (L3): 4 X buffers, distance-2 prefetch, phase-stable.
template<int CI, int CO, int MW>
__global__ __launch_bounds__(256, MW) void k_mfma_dual4(const unsigned short* __restrict__ X,
                                                        const unsigned short* __restrict__ Wp,
                                                        unsigned short* __restrict__ Za,
                                                        unsigned short* __restrict__ Zb,
                                                        float* __restrict__ Sa,
                                                        float* __restrict__ Sb) {
    constexpr int NCH = 4;
    constexpr int KT = CI/32;
    constexpr int WCNT = NCH*KT*512;
    constexpr int ROWT = RR/64;
    constexpr int STR = NCH*16 + 8;
    constexpr int XW  = (CI < 64) ? CI : 64;
    constexpr int PLB = CO/64;
    __shared__ unsigned short scr[4][16*STR];
    int tid = threadIdx.x;
    int lane = tid & 63, wid = tid >> 6;
    int ch = blockIdx.y;
    int wglob = blockIdx.x*4 + wid;
    int NW = gridDim.x*4;
    int n = lane & 15, kq = lane >> 4;
    int rg = lane >> 3, c8l = (lane & 7)*8;
    unsigned short* myscr = scr[wid];
    size_t pl = (size_t)(wglob & (SPL-1)) * 512;
    bool isA = (ch < PLB);
    unsigned short* Zp = (isA ? Za : Zb) + (size_t)(isA ? ch : ch - PLB)*((size_t)RR*64);

    // W direct from global (L2-resident, coalesced 16B/lane) into registers
    half8v wreg[KT][NCH];
    {
        const unsigned short* Wc = Wp + (size_t)ch*WCNT;
#pragma unroll
        for (int kt = 0; kt < KT; ++kt)
#pragma unroll
            for (int j = 0; j < NCH; ++j)
                wreg[kt][j] = *(const half8v*)&Wc[(j*KT + kt)*512 + lane*8];
    }

    float4v ps[NCH], pq[NCH];
#pragma unroll
    for (int j = 0; j < NCH; ++j) { ps[j] = (float4v){0,0,0,0}; pq[j] = (float4v){0,0,0,0}; }

    auto issue = [&](half8v (&dst)[4], size_t rowb, int kt) {
        int k0 = kt*32 + kq*8;
        int xpl = k0 >> 6;
        int xoff = k0 & (XW-1);
        const unsigned short* Xp = X + (size_t)xpl*((size_t)RR*64);
#pragma unroll
        for (int i = 0; i < 4; ++i)
            dst[i] = *(const half8v*)&Xp[(rowb + i*16 + n)*XW + xoff];
    };

    auto domfma = [&](float4v (&acc)[4][NCH], half8v (&wk)[NCH], half8v (&bc)[4]) {
#pragma unroll
        for (int j = 0; j < NCH; ++j)
#pragma unroll
            for (int i = 0; i < 4; ++i)
                acc[i][j] = __builtin_amdgcn_mfma_f32_16x16x32_f16(wk[j], bc[i], acc[i][j], 0, 0, 0);
    };

    auto epilogue = [&](float4v (&acc)[4][NCH], size_t rowbase) {
#pragma unroll
        for (int j = 0; j < NCH; ++j)
#pragma unroll
            for (int i = 0; i < 4; ++i) {
                float4v a4 = acc[i][j];
#pragma unroll
                for (int reg = 0; reg < 4; ++reg) {
                    ps[j][reg] += a4[reg];
                    pq[j][reg] = fmaf(a4[reg], a4[reg], pq[j][reg]);
                }
            }
#pragma unroll
        for (int i = 0; i < 4; ++i) {
            __builtin_amdgcn_wave_barrier();
#pragma unroll
            for (int j = 0; j < NCH; ++j) {
                float4v a4 = acc[i][j];
                ushort4 h = { f2h(a4[0]), f2h(a4[1]), f2h(a4[2]), f2h(a4[3]) };
                *(ushort4*)&myscr[n*STR + j*16 + kq*4] = h;
            }
            __builtin_amdgcn_wave_barrier();
#pragma unroll
            for (int i2 = 0; i2 < 2; ++i2) {
                int rit = rg + i2*8;
                ushort8v v = *(const ushort8v*)&myscr[rit*STR + c8l];
                *(ushort8v*)&Zp[(rowbase + i*16 + rit)*64 + c8l] = v;
            }
        }
    };

    if constexpr (KT == 1) {
        half8v b0[4], b1[4];
        for (int t = wglob; t < ROWT; t += 2*NW) {
            int tB = t + NW;
            size_t rbA = (size_t)t*64;
            issue(b0, rbA, 0);
            bool hasB = (tB < ROWT);
            size_t rbB = hasB ? (size_t)tB*64 : rbA;
            if (hasB) issue(b1, rbB, 0);
            {
                float4v acc[4][NCH];
#pragma unroll
                for (int i = 0; i < 4; ++i)
#pragma unroll
                    for (int j = 0; j < NCH; ++j) acc[i][j] = (float4v){0,0,0,0};
                domfma(acc, wreg[0], b0);
                epilogue(acc, rbA);
            }
            if (hasB) {
                float4v acc[4][NCH];
#pragma unroll
                for (int i = 0; i < 4; ++i)
#pragma unroll
                    for (int j = 0; j < NCH; ++j) acc[i][j] = (float4v){0,0,0,0};
                domfma(acc, wreg[0], b1);
                epilogue(acc, rbB);
            }
        }
    } else if constexpr (KT == 4) {
        half8v p0[4], p1[4], p2[4], p3[4];
        int t = wglob;
        if (t < ROWT) {
            issue(p0, (size_t)t*64, 0);
            issue(p1, (size_t)t*64, 1);
        }
        for (; t < ROWT; t += NW) {
            size_t rowbase = (size_t)t*64;
            int t2 = t + NW;
            size_t nextrb = (t2 < ROWT) ? (size_t)t2*64 : rowbase;
            float4v acc[4][NCH];
#pragma unroll
            for (int i = 0; i < 4; ++i)
#pragma unroll
                for (int j = 0; j < NCH; ++j) acc[i][j] = (float4v){0,0,0,0};
            issue(p2, rowbase, 2);  domfma(acc, wreg[0], p0);
            issue(p3, rowbase, 3);  domfma(acc, wreg[1], p1);
            issue(p0, nextrb, 0);   domfma(acc, wreg[2], p2);
            issue(p1, nextrb, 1);   domfma(acc, wreg[3], p3);
            epilogue(acc, rowbase);
        }
    } else {
        half8v b0[4], b1[4];
        int t = wglob;
        if (t < ROWT) issue(b0, (size_t)t*64, 0);
        for (; t < ROWT; t += NW) {
            size_t rowbase = (size_t)t*64;
            int t2 = t + NW;
            size_t nextrb = (t2 < ROWT) ? (size_t)t2*64 : rowbase;
            float4v acc[4][NCH];
#pragma unroll
            for (int i = 0; i < 4; ++i)
#pragma unroll
                for (int j = 0; j < NCH; ++j) acc[i][j] = (float4v){0,0,0,0};
            issue(b1, rowbase, 1);  domfma(acc, wreg[0], b0);
            issue(b0, nextrb, 0);   domfma(acc, wreg[1], b1);
            epilogue(acc, rowbase);
        }
    }

    {
        float* Sg = isA ? Sa : Sb;
        int cb0 = isA ? ch*64 : ch*64 - CO;
#pragma unroll
        for (int j = 0; j < NCH; ++j) {
#pragma unroll
            for (int reg = 0; reg < 4; ++reg) {
                float s = ps[j][reg], q = pq[j][reg];
                s += __shfl_xor(s, 1, 64); q += __shfl_xor(q, 1, 64);
                s += __shfl_xor(s, 2, 64); q += __shfl_xor(q, 2, 64);
                s += __shfl_xor(s, 4, 64); q += __shfl_xor(q, 4, 64);
                s += __shfl_xor(s, 8, 64); q += __shfl_xor(q, 8, 64);
                if (n == 0) {
                    int col = cb0 + j*16 + kq*4 + reg;
                    atomicAdd(&Sg[pl + col], s);
                    atomicAdd(&Sg[pl + CO + col], q);
                }
            }
        }
    }
}

// ---- fold 64 stat planes into plane 0 for both BN slots of a layer.
// Wave-per-column: 64 lanes each read one plane, shfl-xor tree reduce.
// Critical path: 1 load + 6 shuffles (was 63 serial accumulating loads). ----
template<int CO>
__global__ __launch_bounds__(256) void k_redstats(float* __restrict__ Sa,
                                                  float* __restrict__ Sb) {
    int tid = threadIdx.x;
    int lane = tid & 63;
    int wv = blockIdx.x*4 + (tid >> 6);   // global wave index
    int total = 4*CO;                     // Sa: 2*CO entries, Sb: 2*CO entries
    if (wv >= total) return;
    bool isB = (wv >= 2*CO);
    int u = isB ? (wv - 2*CO) : wv;
    float* Sg = isB ? Sb : Sa;
    float v = Sg[(size_t)lane*512 + u];   // lane = plane index (SPL == 64)
#pragma unroll
    for (int off = 32; off >= 1; off >>= 1) v += __shfl_xor(v, off, 64);
    if (lane == 0) Sg[u] = v;
}

// ---- fused: BN finalize + BNa+lrelu center + gather-max(BNb+lrelu) + add
// + cat contribution. Packed-fp16 sign-folded max. (plane,batch)-combo block
// mapping pins each gather slab (2MB) to one XCD. (Nontemporal hints on the
// streaming accesses were tested and slightly REGRESSED — nt stores defeat
// reuse of x-writeback lines by the next layer's GEMM; reverted.)
// WRITEBACK=false for the last layer (x3 dead after the cat dot).
template<int CO, bool WRITEBACK>
__global__ __launch_bounds__(256) void k_gathermax(unsigned short* __restrict__ xi,
                                                   const unsigned short* __restrict__ zbh,
                                                   const int* __restrict__ ei,
                                                   const float* __restrict__ Sa,
                                                   const float* __restrict__ Sb,
                                                   const float* __restrict__ ga,
                                                   const float* __restrict__ ba,
                                                   const float* __restrict__ gb,
                                                   const float* __restrict__ bbp,
                                                   const float* __restrict__ Wc,
                                                   int wcoff,
                                                   float* __restrict__ zc) {
    constexpr int P = CO/64;                 // planes
    __shared__ float sca[CO], sha[CO], sbA[CO], shb[CO], swc[CO];
    __shared__ __attribute__((aligned(16))) unsigned short smk[CO];
    int tid = threadIdx.x;
    for (int u = tid; u < CO; u += 256) {
        float m = Sa[u]*(1.f/RR);
        float v = fmaxf(Sa[CO+u]*(1.f/RR) - m*m, 0.f);
        float sc = ga[u]*rsqrtf(v + 1e-5f);
        sca[u] = sc; sha[u] = fmaf(-m, sc, ba[u]);
        m = Sb[u]*(1.f/RR);
        v = fmaxf(Sb[CO+u]*(1.f/RR) - m*m, 0.f);
        sc = gb[u]*rsqrtf(v + 1e-5f);
        sbA[u] = fabsf(sc);
        smk[u] = (sc >= 0.f) ? (unsigned short)0 : (unsigned short)0x8000;
        shb[u] = fmaf(-m, sc, bbp[u]);
        swc[u] = Wc[wcoff + u];
    }
    __syncthreads();
    // (plane,batch)-combo partitioning, combos pinned to XCDs (bx & 7)
    int bx = blockIdx.x;
    int xcd = bx & 7;
    int idx = bx >> 3;
    int combo, inner;
    if constexpr (P == 4) {        // 16 combos, grid 8192: 2 combos per XCD
        combo = xcd*2 + (idx >> 9);
        inner = idx & 511;
    } else if constexpr (P == 2) { // 8 combos, grid 4096: 1 combo per XCD
        combo = xcd;
        inner = idx;
    } else {                       // 4 combos, grid 2048: 2 XCDs per combo
        combo = xcd >> 1;
        inner = (idx << 1) | (xcd & 1);
    }
    int pln = combo >> 2;          // combo = pln*BB + b
    int b   = combo & 3;
    int t = inner*256 + tid;       // 0..131071 within combo
    int n = t >> 3;
    int sub = t & 7;
    int c8 = pln*64 + sub*8;
    int off = sub*8;
    int r = (b << 14) | n;
    const unsigned short* zpl = zbh + (size_t)pln*((size_t)RR*64);
    unsigned short* xpl = xi + (size_t)pln*((size_t)RR*64);
    const int4* nb4 = (const int4*)(ei + (size_t)b*2*EE + EE + n*KK);
    int4 q0 = nb4[0], q1 = nb4[1];
    int nbr[KK] = {q0.x,q0.y,q0.z,q0.w,q1.x,q1.y,q1.z,q1.w};
    size_t bb64 = ((size_t)(b<<14))*64 + off;
    ushort8v* xp = (ushort8v*)&xpl[(size_t)r*64 + off];
    ushort8v a = *xp;
    ushort8v u[KK];
#pragma unroll
    for (int k = 0; k < KK; ++k)
        u[k] = *(const ushort8v*)(zpl + bb64 + (size_t)nbr[k]*64);
    // packed fp16 sign-folded max
    ushort8v msk8 = *(const ushort8v*)&smk[c8];
    ushort8v ninfu = {0xFC00,0xFC00,0xFC00,0xFC00,0xFC00,0xFC00,0xFC00,0xFC00};
    half8v mh = __builtin_bit_cast(half8v, ninfu);
#pragma unroll
    for (int k = 0; k < KK; ++k) {
        ushort8v uk = u[k] ^ msk8;
        mh = h8max(mh, __builtin_bit_cast(half8v, uk));
    }
    float sb[8], hb[8];
#pragma unroll
    for (int j = 0; j < 8; ++j) { sb[j] = sbA[c8+j]; hb[j] = shb[c8+j]; }
    float sdot = 0.f;
    if (WRITEBACK) {
        ushort8v o;
#pragma unroll
        for (int j = 0; j < 8; ++j) {
            int c = c8 + j;
            float y = lrelu(fmaf((float)mh[j], sb[j], hb[j]));
            float val = lrelu(fmaf(h2f(a[j]), sca[c], sha[c])) + y;
            o[j] = f2h(val);
            sdot = fmaf(val, swc[c], sdot);
        }
        *xp = o;
    } else {
#pragma unroll
        for (int j = 0; j < 8; ++j) {
            int c = c8 + j;
            float y = lrelu(fmaf((float)mh[j], sb[j], hb[j]));
            float val = lrelu(fmaf(h2f(a[j]), sca[c], sha[c])) + y;
            sdot = fmaf(val, swc[c], sdot);
        }
    }
    // reduce the 8 sub-lanes of this row (contiguous lanes)
    sdot += __shfl_xor(sdot, 1, 64);
    sdot += __shfl_xor(sdot, 2, 64);
    sdot += __shfl_xor(sdot, 4, 64);
    if (sub == 0) atomicAdd(&zc[r], sdot);
}

// ---- cat head stats: sum/sumsq of zc into 256 plane-pairs ----
__global__ __launch_bounds__(256) void k_catstats(const float* __restrict__ zc,
                                                  float* __restrict__ S8) {
    __shared__ float rs2[2];
    int tid = threadIdx.x;
    if (tid < 2) rs2[tid] = 0.f;
    __syncthreads();
    float v = zc[blockIdx.x*256 + tid];
    float s = v, q = v*v;
#pragma unroll
    for (int off = 32; off >= 1; off >>= 1) {
        s += __shfl_xor(s, off, 64);
        q += __shfl_xor(q, off, 64);
    }
    if ((tid & 63) == 0) { atomicAdd(&rs2[0], s); atomicAdd(&rs2[1], q); }
    __syncthreads();
    if (tid == 0) {
        int p = blockIdx.x & 255;
        atomicAdd(&S8[p*2],     rs2[0]);
        atomicAdd(&S8[p*2 + 1], rs2[1]);
    }
}

// ---- final: reduce 256 plane-pairs, BN(1 col) + leaky + bias ----
__global__ __launch_bounds__(256) void k_catfinal(const float* __restrict__ zc,
                                                  const float* __restrict__ S8,
                                                  const float* __restrict__ g,
                                                  const float* __restrict__ bb,
                                                  const float* __restrict__ bias,
                                                  float* __restrict__ out) {
    __shared__ float rs[256], rq[256];
    int tid = threadIdx.x;
    rs[tid] = S8[tid*2];
    rq[tid] = S8[tid*2 + 1];
    __syncthreads();
#pragma unroll
    for (int h = 128; h >= 1; h >>= 1) {
        if (tid < h) { rs[tid] += rs[tid+h]; rq[tid] += rq[tid+h]; }
        __syncthreads();
    }
    int r = blockIdx.x*256 + tid;
    const float invR = 1.f/65536.f;
    float m = rs[0]*invR;
    float v = fmaxf(rq[0]*invR - m*m, 0.f);
    float sc = g[0]*rsqrtf(v + 1e-5f);
    float sh = fmaf(-m, sc, bb[0]);
    float y = lrelu(fmaf(zc[r], sc, sh));
    out[r] = y + bias[0];
}

extern "C" void kernel_launch(void* const* d_in, const int* in_sizes, int n_in,
                              void* d_out, int out_size, void* d_ws, size_t ws_size,
                              hipStream_t stream) {
    const float* x    = (const float*)d_in[0];
    const int*   ei   = (const int*)d_in[1];
    const float* W0a  = (const float*)d_in[2];
    const float* g0a  = (const float*)d_in[3];
    const float* b0a  = (const float*)d_in[4];
    const float* W0b  = (const float*)d_in[5];
    const float* g0b  = (const float*)d_in[6];
    const float* b0b  = (const float*)d_in[7];
    const float* W1a  = (const float*)d_in[8];
    const float* g1a  = (const float*)d_in[9];
    const float* b1a  = (const float*)d_in[10];
    const float* W1b  = (const float*)d_in[11];
    const float* g1b  = (const float*)d_in[12];
    const float* b1b  = (const float*)d_in[13];
    const float* W2a  = (const float*)d_in[14];
    const float* g2a  = (const float*)d_in[15];
    const float* b2a  = (const float*)d_in[16];
    const float* W2b  = (const float*)d_in[17];
    const float* g2b  = (const float*)d_in[18];
    const float* b2b  = (const float*)d_in[19];
    const float* W3a  = (const float*)d_in[20];
    const float* g3a  = (const float*)d_in[21];
    const float* b3a  = (const float*)d_in[22];
    const float* W3b  = (const float*)d_in[23];
    const float* g3b  = (const float*)d_in[24];
    const float* b3b  = (const float*)d_in[25];
    const float* Wcat = (const float*)d_in[26];
    const float* gcat = (const float*)d_in[27];
    const float* bcat = (const float*)d_in[28];
    const float* bias = (const float*)d_in[29];
    float* out = (float*)d_out;

    float* ws = (float*)d_ws;
    unsigned short* x0 = (unsigned short*)(ws + OFF_X0);
    unsigned short* x1 = (unsigned short*)(ws + OFF_X1);
    unsigned short* x2 = (unsigned short*)(ws + OFF_X2);
    unsigned short* x3 = (unsigned short*)(ws + OFF_X3);
    unsigned short* zbh = (unsigned short*)(ws + OFF_ZB);
    float* zc = ws + OFF_ZC;
    float* S  = ws + OFF_S;
    unsigned short* wpbase = (unsigned short*)(ws + OFF_WP);
    unsigned short* wp1 = wpbase + WP1_OFF;
    unsigned short* wp2 = wpbase + WP2_OFF;
    unsigned short* wp3 = wpbase + WP3_OFF;
    float* mxb = ws + OFF_MX;
    auto Sl = [&](int i) { return S + (size_t)i*SLOT; };

    // ---- fused weight prep + stats zero ----
    k_prep<<<256, 256, 0, stream>>>(W1a, W1b, W2a, W2b, W3a, W3b, wp1, wp2, wp3, S);

    // ---- layer 0: fused single-gather-pass, then streaming finalize ----
    k_l0_fused<<<RR*4/256, 256, 0, stream>>>(x, ei, W0a, W0b, g0b, x0, mxb, Sl(0), Sl(1));
    k_edge_apply2<<<RR/256, 256, 0, stream>>>(mxb, Sl(0), Sl(1),
                                              g0a, b0a, g0b, b0b, Wcat, x0, zc);

    // ---- layer 1: 32 -> 64 (reg-W, 2 tiles/wave pipelined) ----
    k_mfma_dual4<32,64,3><<<dim3(128,2), 256, 0, stream>>>(x0, wp1, x1, zbh, Sl(2), Sl(3));
    k_redstats<64><<<64, 256, 0, stream>>>(Sl(2), Sl(3));
    k_gathermax<64,true><<<RR*8/256, 256, 0, stream>>>(x1, zbh, ei, Sl(2), Sl(3),
                                                       g1a, b1a, g1b, b1b, Wcat, 32, zc);

    // ---- layer 2: 64 -> 128 (reg-W, distance-1 ping-pong) ----
    k_mfma_dual4<64,128,3><<<dim3(128,4), 256, 0, stream>>>(x1, wp2, x2, zbh, Sl(4), Sl(5));
    k_redstats<128><<<128, 256, 0, stream>>>(Sl(4), Sl(5));
    k_gathermax<128,true><<<RR*16/256, 256, 0, stream>>>(x2, zbh, ei, Sl(4), Sl(5),
                                                         g2a, b2a, g2b, b2b, Wcat, 96, zc);

    // ---- layer 3: 128 -> 256 (reg-W, distance-2 prefetch, 4 tiles/wave) ----
    k_mfma_dual4<128,256,2><<<dim3(64,8), 256, 0, stream>>>(x2, wp3, x3, zbh, Sl(6), Sl(7));
    k_redstats<256><<<256, 256, 0, stream>>>(Sl(6), Sl(7));
    k_gathermax<256,false><<<RR*32/256, 256, 0, stream>>>(x3, zbh, ei, Sl(6), Sl(7),
                                                          g3a, b3a, g3b, b3b, Wcat, 224, zc);

    // ---- cat head (two-kernel: catstats + catfinal — the fused single-kernel
    // variant was tested and regressed ~10us: 256-block redundant full-reduce
    // is latency-bound at 1 block/CU) ----
    k_catstats<<<RR/256, 256, 0, stream>>>(zc, Sl(8));
    k_catfinal<<<RR/256, 256, 0, stream>>>(zc, Sl(8), gcat, bcat, bias, out);
}